// Round 5
// baseline (245.257 us; speedup 1.0000x reference)
//
#include <hip/hip_runtime.h>
#include <stdint.h>

#define BB 4
#define TT 2048
#define HH 1024
#define NN 16
#define KK 1024           // GEMM K  (= H)
#define GG 1024           // GEMM out cols (= H)
#define MM (BB*TT)        // GEMM rows
#define NCHUNK 8
#define TC (TT/NCHUNK)    // 256 timesteps per chunk

#if __has_builtin(__builtin_amdgcn_exp2f)
#define FAST_EXP2(x) __builtin_amdgcn_exp2f(x)
#else
#define FAST_EXP2(x) __expf((x) * 0.6931471805599453f)
#endif
#define EXPSCALE 1.4426950408889634f

typedef __attribute__((ext_vector_type(8))) short short8;
typedef __attribute__((ext_vector_type(4))) float f32x4;

__device__ __forceinline__ unsigned short f2bf(float f) {
  union { float f; unsigned u; } a; a.f = f;
  unsigned u = a.u;
  u += 0x7fffu + ((u >> 16) & 1u);   // round-to-nearest-even
  return (unsigned short)(u >> 16);
}

__global__ __launch_bounds__(256) void cvt_f32_bf16(const float* __restrict__ src,
                                                    unsigned short* __restrict__ dst, int n4) {
  int i = blockIdx.x * blockDim.x + threadIdx.x;
  if (i >= n4) return;
  float4 a = ((const float4*)src)[i];
  ushort4 o;
  o.x = f2bf(a.x); o.y = f2bf(a.y); o.z = f2bf(a.z); o.w = f2bf(a.w);
  ((ushort4*)dst)[i] = o;
}

// dtT[b,h,t] = softplus( sum_k x[(b,t),k]*W[h,k] + b_dt[h] )  -- transposed output
__global__ __launch_bounds__(256) void gemm_dt(const unsigned short* __restrict__ xb,
                                               const unsigned short* __restrict__ wb,
                                               const float* __restrict__ b_dt,
                                               float* __restrict__ dtT) {
  __shared__ short lsA[128 * 32];
  __shared__ short lsB[128 * 32];
  const int tid  = threadIdx.x;
  const int w    = tid >> 6;
  const int lane = tid & 63;
  const int m0 = blockIdx.x * 128;
  const int g0 = blockIdx.y * 128;

  const int e0  = w * 1024 + lane * 8;
  const int am0 = e0 >> 5,        ak0 = e0 & 31;
  const int am1 = (e0 + 512) >> 5, ak1 = (e0 + 512) & 31;
  const unsigned short* gA0 = xb + (size_t)(m0 + am0) * KK + ak0;
  const unsigned short* gA1 = xb + (size_t)(m0 + am1) * KK + ak1;
  const unsigned short* gB0 = wb + (size_t)(g0 + am0) * KK + ak0;
  const unsigned short* gB1 = wb + (size_t)(g0 + am1) * KK + ak1;
  short* lA0 = lsA + w * 1024;
  short* lB0 = lsB + w * 1024;

  const int wm   = (w >> 1) * 64;
  const int wg   = (w & 1) * 64;
  const int lrow = lane & 15;
  const int lq   = lane >> 4;

  f32x4 acc[4][4];
  const f32x4 zero = {0.f, 0.f, 0.f, 0.f};
#pragma unroll
  for (int i = 0; i < 4; ++i)
#pragma unroll
    for (int j = 0; j < 4; ++j) acc[i][j] = zero;

  for (int kt = 0; kt < KK / 32; ++kt) {
    const int ko = kt * 32;
    __builtin_amdgcn_global_load_lds((__attribute__((address_space(1))) void*)(gA0 + ko),
                                     (__attribute__((address_space(3))) void*)(lA0), 16, 0, 0);
    __builtin_amdgcn_global_load_lds((__attribute__((address_space(1))) void*)(gA1 + ko),
                                     (__attribute__((address_space(3))) void*)(lA0 + 512), 16, 0, 0);
    __builtin_amdgcn_global_load_lds((__attribute__((address_space(1))) void*)(gB0 + ko),
                                     (__attribute__((address_space(3))) void*)(lB0), 16, 0, 0);
    __builtin_amdgcn_global_load_lds((__attribute__((address_space(1))) void*)(gB1 + ko),
                                     (__attribute__((address_space(3))) void*)(lB0 + 512), 16, 0, 0);
    __syncthreads();

    short8 af[4], bfr[4];
#pragma unroll
    for (int mi = 0; mi < 4; ++mi)
      af[mi] = *(const short8*)&lsA[(wm + mi * 16 + lrow) * 32 + lq * 8];
#pragma unroll
    for (int ni = 0; ni < 4; ++ni)
      bfr[ni] = *(const short8*)&lsB[(wg + ni * 16 + lrow) * 32 + lq * 8];
#pragma unroll
    for (int mi = 0; mi < 4; ++mi)
#pragma unroll
      for (int ni = 0; ni < 4; ++ni)
        acc[mi][ni] = __builtin_amdgcn_mfma_f32_16x16x32_bf16(af[mi], bfr[ni], acc[mi][ni], 0, 0, 0);
    __syncthreads();
  }

  // epilogue: 4 consecutive t per lane-fragment -> float4 store into [B,H,T]
  const int b  = m0 >> 11;                      // T=2048 rows per batch, m0 128-aligned
  const int tb = (m0 & (TT - 1)) + wm + lq * 4;
#pragma unroll
  for (int mi = 0; mi < 4; ++mi)
#pragma unroll
    for (int ni = 0; ni < 4; ++ni) {
      const int gcol = g0 + wg + ni * 16 + lrow;
      const float bias = b_dt[gcol];
      f32x4 sp;
#pragma unroll
      for (int r = 0; r < 4; ++r) {
        float z = acc[mi][ni][r] + bias;
        sp[r] = (z > 15.f) ? z : log1pf(__expf(z));
      }
      *(f32x4*)&dtT[((size_t)b * HH + gcol) * TT + tb + mi * 16] = sp;
    }
}

// butterfly reduce-scatter over the 16-lane group: lane n ends with sum_p v_p[n]
__device__ __forceinline__ float reduce16(float (&v)[16], int n16) {
#pragma unroll
  for (int i = 0; i < 8; ++i) {
    float lo = v[i], hi = v[i + 8];
    float snd = (n16 & 8) ? lo : hi;
    float rcv = __shfl_xor(snd, 8);
    v[i] = ((n16 & 8) ? hi : lo) + rcv;
  }
#pragma unroll
  for (int i = 0; i < 4; ++i) {
    float lo = v[i], hi = v[i + 4];
    float snd = (n16 & 4) ? lo : hi;
    float rcv = __shfl_xor(snd, 4);
    v[i] = ((n16 & 4) ? hi : lo) + rcv;
  }
#pragma unroll
  for (int i = 0; i < 2; ++i) {
    float lo = v[i], hi = v[i + 2];
    float snd = (n16 & 2) ? lo : hi;
    float rcv = __shfl_xor(snd, 2);
    v[i] = ((n16 & 2) ? hi : lo) + rcv;
  }
  float lo = v[0], hi = v[1];
  float snd = (n16 & 1) ? lo : hi;
  float rcv = __shfl_xor(snd, 1);
  return ((n16 & 1) ? hi : lo) + rcv;
}

// pull u[t=k] from lane g4*16+k of this wave
__device__ __forceinline__ float bcast16(float ureg, int idxbyte) {
  union { float f; int i; } a, r; a.f = ureg;
  r.i = __builtin_amdgcn_ds_bpermute(idxbyte, a.i);
  return r.f;
}

// ---- exp-basis (chain-free) 16-step groups -------------------------------
// Within a group, with group-local cumsum c_t (inclusive):
//   s_t = E_t * (s_in + Bm * P_t),  E_t = exp2(Ae*c_t),
//   P_t = sum_{t'<=t} dt*u*exp2(-Ae*c_t')   (Bm factored out)
// Group end: s_in' = s_15. All exps independent; only P has a (2-cyc) chain.

__device__ __forceinline__ void group16_p1(float& s, float& sd, const f32x4* dd, float ureg,
                                           int idxb, float Ae, float Bm) {
  float P = 0.f, cg = 0.f;
#pragma unroll
  for (int q = 0; q < 4; ++q) {
#pragma unroll
    for (int k = 0; k < 4; ++k) {
      const int kk = q * 4 + k;
      float dtv = dd[q][k];
      cg += dtv;
      float uv = bcast16(ureg, idxb + kk * 4);
      float Einv = FAST_EXP2(-Ae * cg);
      P = fmaf(dtv * uv, Einv, P);
    }
  }
  float EL = FAST_EXP2(Ae * cg);
  s = EL * fmaf(Bm, P, s);
  sd += cg;
}

__device__ __forceinline__ void group16_p3(float& s, const f32x4* dd, float ureg, int idxb,
                                           float Ae, float Bm, float Cc, float Dmask,
                                           int n16, float* __restrict__ yp) {
  float v[16];
  float P = 0.f, cg = 0.f;
  float st = s;
#pragma unroll
  for (int q = 0; q < 4; ++q) {
#pragma unroll
    for (int k = 0; k < 4; ++k) {
      const int kk = q * 4 + k;
      float dtv = dd[q][k];
      cg += dtv;
      float uv = bcast16(ureg, idxb + kk * 4);
      float Einv = FAST_EXP2(-Ae * cg);
      float E    = FAST_EXP2(Ae * cg);
      P = fmaf(dtv * uv, Einv, P);
      st = E * fmaf(Bm, P, s);
      v[kk] = fmaf(Dmask, uv, Cc * st);
    }
  }
  s = st;
  *yp = reduce16(v, n16);
}

// ---- chunk-parallel scan, transposed dt + shuffle-broadcast u ------------
// block: 256 threads = 16 h x 16 n. grid: 64 h-tiles x 4 b x NCHUNK c.
__global__ __launch_bounds__(256) void ssm_phase1(const float* __restrict__ x,
                                                  const float* __restrict__ dtT,
                                                  const float* __restrict__ A_log,
                                                  const float* __restrict__ Bm_,
                                                  float* __restrict__ sloc,
                                                  float* __restrict__ decay) {
  const int tid = threadIdx.x;
  const int g   = tid >> 4;
  const int n16 = tid & 15;
  const int bid = blockIdx.x;
  const int ht  = bid & 63;
  const int b   = (bid >> 6) & 3;
  const int c   = bid >> 8;
  const int h   = (ht << 4) + g;
  const int lane = tid & 63;
  const int tl   = lane & 15;
  const int idxb = (lane & 48) << 2;   // (lane>>4)*16*4

  const float Aneg = -__expf(A_log[h * NN + n16]);
  const float Ae   = Aneg * EXPSCALE;
  const float Bm   = Bm_[h * NN + n16];

  const f32x4* dp4 = (const f32x4*)(dtT + ((size_t)b * HH + h) * TT + c * TC);
  const float* up  = x + (size_t)b * TT * HH + (size_t)(c * TC + tl) * HH + h;

  float s = 0.f, sd = 0.f;
  f32x4 d0[4], d1[4];
  float u0, u1;
#pragma unroll
  for (int i = 0; i < 4; ++i) d0[i] = dp4[i];
  u0 = up[0];

#pragma unroll 1
  for (int j = 0; j < TC / 16; j += 2) {
#pragma unroll
    for (int i = 0; i < 4; ++i) d1[i] = dp4[(j + 1) * 4 + i];
    u1 = up[(size_t)(j + 1) * 16 * HH];
    group16_p1(s, sd, d0, u0, idxb, Ae, Bm);
    if (j + 2 < TC / 16) {
#pragma unroll
      for (int i = 0; i < 4; ++i) d0[i] = dp4[(j + 2) * 4 + i];
      u0 = up[(size_t)(j + 2) * 16 * HH];
    }
    group16_p1(s, sd, d1, u1, idxb, Ae, Bm);
  }

  const size_t idx = (((size_t)c * BB + b) * HH + h) * NN + n16;
  sloc[idx]  = s;
  decay[idx] = FAST_EXP2(Ae * sd);
}

// phase 2: sequential combine over chunks; sloc becomes carry-in per chunk.
__global__ __launch_bounds__(256) void ssm_phase2(float* __restrict__ sloc,
                                                  const float* __restrict__ decay,
                                                  float* __restrict__ stateOut) {
  const int id = blockIdx.x * 256 + threadIdx.x;   // (b,h,n) flat, 65536
  float carry = 0.f;
#pragma unroll
  for (int c = 0; c < NCHUNK; ++c) {
    const size_t idx = (size_t)c * (BB * HH * NN) + id;
    const float sl = sloc[idx];
    const float dc = decay[idx];
    sloc[idx] = carry;
    carry = fmaf(dc, carry, sl);
  }
  stateOut[id] = carry;
}

// phase 3: scan each chunk from its carry-in, emitting y.
__global__ __launch_bounds__(256) void ssm_phase3(const float* __restrict__ x,
                                                  const float* __restrict__ dtT,
                                                  const float* __restrict__ A_log,
                                                  const float* __restrict__ Bm_,
                                                  const float* __restrict__ Cm_,
                                                  const float* __restrict__ Dv_,
                                                  const float* __restrict__ carryBuf,
                                                  float* __restrict__ out) {
  const int tid = threadIdx.x;
  const int g   = tid >> 4;
  const int n16 = tid & 15;
  const int bid = blockIdx.x;
  const int ht  = bid & 63;
  const int b   = (bid >> 6) & 3;
  const int c   = bid >> 8;
  const int h   = (ht << 4) + g;
  const int lane = tid & 63;
  const int tl   = lane & 15;
  const int idxb = (lane & 48) << 2;

  const float Aneg  = -__expf(A_log[h * NN + n16]);
  const float Ae    = Aneg * EXPSCALE;
  const float Bm    = Bm_[h * NN + n16];
  const float Cc    = Cm_[h * NN + n16];
  const float Dmask = (n16 == 0) ? Dv_[h] : 0.f;

  const f32x4* dp4 = (const f32x4*)(dtT + ((size_t)b * HH + h) * TT + c * TC);
  const float* up  = x + (size_t)b * TT * HH + (size_t)(c * TC + tl) * HH + h;
  float* yp = out + (size_t)b * TT * HH + (size_t)(c * TC + n16) * HH + h;

  float s = carryBuf[(((size_t)c * BB + b) * HH + h) * NN + n16];
  f32x4 d0[4], d1[4];
  float u0, u1;
#pragma unroll
  for (int i = 0; i < 4; ++i) d0[i] = dp4[i];
  u0 = up[0];

#pragma unroll 1
  for (int j = 0; j < TC / 16; j += 2) {
#pragma unroll
    for (int i = 0; i < 4; ++i) d1[i] = dp4[(j + 1) * 4 + i];
    u1 = up[(size_t)(j + 1) * 16 * HH];
    group16_p3(s, d0, u0, idxb, Ae, Bm, Cc, Dmask, n16, yp);
    yp += 16 * HH;
    if (j + 2 < TC / 16) {
#pragma unroll
      for (int i = 0; i < 4; ++i) d0[i] = dp4[(j + 2) * 4 + i];
      u0 = up[(size_t)(j + 2) * 16 * HH];
    }
    group16_p3(s, d1, u1, idxb, Ae, Bm, Cc, Dmask, n16, yp);
    yp += 16 * HH;
  }
}

extern "C" void kernel_launch(void* const* d_in, const int* in_sizes, int n_in,
                              void* d_out, int out_size, void* d_ws, size_t ws_size,
                              hipStream_t stream) {
  const float* x     = (const float*)d_in[0];
  const float* A_log = (const float*)d_in[1];
  const float* B_mat = (const float*)d_in[2];
  const float* C_mat = (const float*)d_in[3];
  const float* D_vec = (const float*)d_in[4];
  const float* W_dt  = (const float*)d_in[5];
  const float* b_dt  = (const float*)d_in[6];
  float* out = (float*)d_out;

  char* ws = (char*)d_ws;
  unsigned short* xb  = (unsigned short*)(ws);                 // 16 MB (dead after gemm)
  unsigned short* wb  = (unsigned short*)(ws + 16777216);      //  2 MB (dead after gemm)
  float*          dtT = (float*)(ws + 18874368);               // 32 MB, [B,H,T]
  // sloc/decay reuse the xb region: gemm completes before phase1 in stream order.
  float*          sloc  = (float*)(ws);                        // 2 MB
  float*          decay = (float*)(ws + 4194304);              // 2 MB
  float* stateOut = out + (size_t)BB * TT * HH;

  cvt_f32_bf16<<<(MM * KK / 4 + 255) / 256, 256, 0, stream>>>(x, xb, MM * KK / 4);
  cvt_f32_bf16<<<(GG * KK / 4 + 255) / 256, 256, 0, stream>>>(W_dt, wb, GG * KK / 4);
  gemm_dt<<<dim3(MM / 128, GG / 128), 256, 0, stream>>>(xb, wb, b_dt, dtT);

  const int nblk = BB * (HH / 16) * NCHUNK;   // 2048
  ssm_phase1<<<nblk, 256, 0, stream>>>(x, dtT, A_log, B_mat, sloc, decay);
  ssm_phase2<<<(BB * HH * NN) / 256, 256, 0, stream>>>(sloc, decay, stateOut);
  ssm_phase3<<<nblk, 256, 0, stream>>>(x, dtT, A_log, B_mat, C_mat, D_vec, sloc, out);
}

// Round 6
// 231.832 us; speedup vs baseline: 1.0579x; 1.0579x over previous
//
#include <hip/hip_runtime.h>
#include <stdint.h>

#define BB 4
#define TT 2048
#define HH 1024
#define NN 16
#define KK 1024           // GEMM K  (= H)
#define GG 1024           // GEMM out cols (= H)
#define MM (BB*TT)        // GEMM rows
#define NCHUNK 16
#define TC (TT/NCHUNK)    // 128 timesteps per chunk

#if __has_builtin(__builtin_amdgcn_exp2f)
#define FAST_EXP2(x) __builtin_amdgcn_exp2f(x)
#else
#define FAST_EXP2(x) __expf((x) * 0.6931471805599453f)
#endif
#define EXPSCALE 1.4426950408889634f

typedef __attribute__((ext_vector_type(8))) short short8;
typedef __attribute__((ext_vector_type(4))) float f32x4;

__device__ __forceinline__ unsigned short f2bf(float f) {
  union { float f; unsigned u; } a; a.f = f;
  unsigned u = a.u;
  u += 0x7fffu + ((u >> 16) & 1u);   // round-to-nearest-even
  return (unsigned short)(u >> 16);
}

__global__ __launch_bounds__(256) void cvt_f32_bf16(const float* __restrict__ src,
                                                    unsigned short* __restrict__ dst, int n4) {
  int i = blockIdx.x * blockDim.x + threadIdx.x;
  if (i >= n4) return;
  float4 a = ((const float4*)src)[i];
  ushort4 o;
  o.x = f2bf(a.x); o.y = f2bf(a.y); o.z = f2bf(a.z); o.w = f2bf(a.w);
  ((ushort4*)dst)[i] = o;
}

// dtT[b,h,t] = softplus( sum_k x[(b,t),k]*W[h,k] + b_dt[h] )  -- transposed output
__global__ __launch_bounds__(256) void gemm_dt(const unsigned short* __restrict__ xb,
                                               const unsigned short* __restrict__ wb,
                                               const float* __restrict__ b_dt,
                                               float* __restrict__ dtT) {
  __shared__ short lsA[128 * 32];
  __shared__ short lsB[128 * 32];
  const int tid  = threadIdx.x;
  const int w    = tid >> 6;
  const int lane = tid & 63;
  const int m0 = blockIdx.x * 128;
  const int g0 = blockIdx.y * 128;

  const int e0  = w * 1024 + lane * 8;
  const int am0 = e0 >> 5,        ak0 = e0 & 31;
  const int am1 = (e0 + 512) >> 5, ak1 = (e0 + 512) & 31;
  const unsigned short* gA0 = xb + (size_t)(m0 + am0) * KK + ak0;
  const unsigned short* gA1 = xb + (size_t)(m0 + am1) * KK + ak1;
  const unsigned short* gB0 = wb + (size_t)(g0 + am0) * KK + ak0;
  const unsigned short* gB1 = wb + (size_t)(g0 + am1) * KK + ak1;
  short* lA0 = lsA + w * 1024;
  short* lB0 = lsB + w * 1024;

  const int wm   = (w >> 1) * 64;
  const int wg   = (w & 1) * 64;
  const int lrow = lane & 15;
  const int lq   = lane >> 4;

  f32x4 acc[4][4];
  const f32x4 zero = {0.f, 0.f, 0.f, 0.f};
#pragma unroll
  for (int i = 0; i < 4; ++i)
#pragma unroll
    for (int j = 0; j < 4; ++j) acc[i][j] = zero;

  for (int kt = 0; kt < KK / 32; ++kt) {
    const int ko = kt * 32;
    __builtin_amdgcn_global_load_lds((__attribute__((address_space(1))) void*)(gA0 + ko),
                                     (__attribute__((address_space(3))) void*)(lA0), 16, 0, 0);
    __builtin_amdgcn_global_load_lds((__attribute__((address_space(1))) void*)(gA1 + ko),
                                     (__attribute__((address_space(3))) void*)(lA0 + 512), 16, 0, 0);
    __builtin_amdgcn_global_load_lds((__attribute__((address_space(1))) void*)(gB0 + ko),
                                     (__attribute__((address_space(3))) void*)(lB0), 16, 0, 0);
    __builtin_amdgcn_global_load_lds((__attribute__((address_space(1))) void*)(gB1 + ko),
                                     (__attribute__((address_space(3))) void*)(lB0 + 512), 16, 0, 0);
    __syncthreads();

    short8 af[4], bfr[4];
#pragma unroll
    for (int mi = 0; mi < 4; ++mi)
      af[mi] = *(const short8*)&lsA[(wm + mi * 16 + lrow) * 32 + lq * 8];
#pragma unroll
    for (int ni = 0; ni < 4; ++ni)
      bfr[ni] = *(const short8*)&lsB[(wg + ni * 16 + lrow) * 32 + lq * 8];
#pragma unroll
    for (int mi = 0; mi < 4; ++mi)
#pragma unroll
      for (int ni = 0; ni < 4; ++ni)
        acc[mi][ni] = __builtin_amdgcn_mfma_f32_16x16x32_bf16(af[mi], bfr[ni], acc[mi][ni], 0, 0, 0);
    __syncthreads();
  }

  // epilogue: 4 consecutive t per lane-fragment -> float4 store into [B,H,T]
  const int b  = m0 >> 11;                      // T=2048 rows per batch, m0 128-aligned
  const int tb = (m0 & (TT - 1)) + wm + lq * 4;
#pragma unroll
  for (int mi = 0; mi < 4; ++mi)
#pragma unroll
    for (int ni = 0; ni < 4; ++ni) {
      const int gcol = g0 + wg + ni * 16 + lrow;
      const float bias = b_dt[gcol];
      f32x4 sp;
#pragma unroll
      for (int r = 0; r < 4; ++r) {
        float z = acc[mi][ni][r] + bias;
        sp[r] = (z > 15.f) ? z : log1pf(__expf(z));
      }
      *(f32x4*)&dtT[((size_t)b * HH + gcol) * TT + tb + mi * 16] = sp;
    }
}

// butterfly reduce-scatter over the 16-lane group: lane n ends with sum_p v_p[n]
__device__ __forceinline__ float reduce16(float (&v)[16], int n16) {
#pragma unroll
  for (int i = 0; i < 8; ++i) {
    float lo = v[i], hi = v[i + 8];
    float snd = (n16 & 8) ? lo : hi;
    float rcv = __shfl_xor(snd, 8);
    v[i] = ((n16 & 8) ? hi : lo) + rcv;
  }
#pragma unroll
  for (int i = 0; i < 4; ++i) {
    float lo = v[i], hi = v[i + 4];
    float snd = (n16 & 4) ? lo : hi;
    float rcv = __shfl_xor(snd, 4);
    v[i] = ((n16 & 4) ? hi : lo) + rcv;
  }
#pragma unroll
  for (int i = 0; i < 2; ++i) {
    float lo = v[i], hi = v[i + 2];
    float snd = (n16 & 2) ? lo : hi;
    float rcv = __shfl_xor(snd, 2);
    v[i] = ((n16 & 2) ? hi : lo) + rcv;
  }
  float lo = v[0], hi = v[1];
  float snd = (n16 & 1) ? lo : hi;
  float rcv = __shfl_xor(snd, 1);
  return ((n16 & 1) ? hi : lo) + rcv;
}

// pull u[t=k] from lane g4*16+k of this wave
__device__ __forceinline__ float bcast16(float ureg, int idxbyte) {
  union { float f; int i; } a, r; a.f = ureg;
  r.i = __builtin_amdgcn_ds_bpermute(idxbyte, a.i);
  return r.f;
}

// sequential recurrence in s' units (Bm folded out): s' = a*s' + dt*u
__device__ __forceinline__ void step16_p1(float& s, float& sd, const f32x4* dd, float ureg,
                                          int idxb, float Ae) {
#pragma unroll
  for (int q = 0; q < 4; ++q) {
#pragma unroll
    for (int k = 0; k < 4; ++k) {
      const int kk = q * 4 + k;
      float dtv = dd[q][k];
      float uv  = bcast16(ureg, idxb + kk * 4);
      float ab  = FAST_EXP2(dtv * Ae);
      s = fmaf(ab, s, dtv * uv);
      sd += dtv;
    }
  }
}

__device__ __forceinline__ void step16_p3(float& s, const f32x4* dd, float ureg, int idxb,
                                          float Ae, float Cb, float Dv,
                                          int n16, float* __restrict__ yp) {
  float v[16];
#pragma unroll
  for (int q = 0; q < 4; ++q) {
#pragma unroll
    for (int k = 0; k < 4; ++k) {
      const int kk = q * 4 + k;
      float dtv = dd[q][k];
      float uv  = bcast16(ureg, idxb + kk * 4);
      float ab  = FAST_EXP2(dtv * Ae);
      s = fmaf(ab, s, dtv * uv);
      v[kk] = Cb * s;
    }
  }
  float y = reduce16(v, n16);
  // lane n16 holds u[t0+n16] natively (tl == n16)
  *yp = fmaf(Dv, ureg, y);
}

// ---- chunk-parallel scan, transposed dt + shuffle-broadcast u ------------
// block: 256 threads = 16 h x 16 n. grid: 64 h-tiles x 4 b x NCHUNK c.
__global__ __launch_bounds__(256) void ssm_phase1(const float* __restrict__ x,
                                                  const float* __restrict__ dtT,
                                                  const float* __restrict__ A_log,
                                                  float* __restrict__ sloc,
                                                  float* __restrict__ decay) {
  const int tid = threadIdx.x;
  const int g   = tid >> 4;
  const int n16 = tid & 15;
  const int bid = blockIdx.x;
  const int ht  = bid & 63;
  const int b   = (bid >> 6) & 3;
  const int c   = bid >> 8;
  const int h   = (ht << 4) + g;
  const int lane = tid & 63;
  const int tl   = lane & 15;
  const int idxb = (lane & 48) << 2;   // (lane>>4)*16*4

  const float Aneg = -__expf(A_log[h * NN + n16]);
  const float Ae   = Aneg * EXPSCALE;

  const f32x4* dp4 = (const f32x4*)(dtT + ((size_t)b * HH + h) * TT + c * TC);
  const float* up  = x + (size_t)b * TT * HH + (size_t)(c * TC + tl) * HH + h;

  float s = 0.f, sd = 0.f;
  f32x4 d0[4], d1[4];
  float u0, u1;
#pragma unroll
  for (int i = 0; i < 4; ++i) d0[i] = dp4[i];
  u0 = up[0];

#pragma unroll 1
  for (int j = 0; j < TC / 16; j += 2) {
#pragma unroll
    for (int i = 0; i < 4; ++i) d1[i] = dp4[(j + 1) * 4 + i];
    u1 = up[(size_t)(j + 1) * 16 * HH];
    step16_p1(s, sd, d0, u0, idxb, Ae);
    if (j + 2 < TC / 16) {
#pragma unroll
      for (int i = 0; i < 4; ++i) d0[i] = dp4[(j + 2) * 4 + i];
      u0 = up[(size_t)(j + 2) * 16 * HH];
    }
    step16_p1(s, sd, d1, u1, idxb, Ae);
  }

  const size_t idx = (((size_t)c * BB + b) * HH + h) * NN + n16;
  sloc[idx]  = s;
  decay[idx] = FAST_EXP2(Ae * sd);
}

// phase 2: sequential combine over chunks (s' units); sloc becomes carry-in.
// stateOut converts back to true state: s = Bm * s'.
__global__ __launch_bounds__(256) void ssm_phase2(float* __restrict__ sloc,
                                                  const float* __restrict__ decay,
                                                  const float* __restrict__ Bm_,
                                                  float* __restrict__ stateOut) {
  const int id = blockIdx.x * 256 + threadIdx.x;   // (b,h,n) flat, 65536
  float carry = 0.f;
#pragma unroll
  for (int c = 0; c < NCHUNK; ++c) {
    const size_t idx = (size_t)c * (BB * HH * NN) + id;
    const float sl = sloc[idx];
    const float dc = decay[idx];
    sloc[idx] = carry;
    carry = fmaf(dc, carry, sl);
  }
  stateOut[id] = Bm_[id & (HH * NN - 1)] * carry;
}

// phase 3: scan each chunk from its carry-in (s' units), emitting y.
__global__ __launch_bounds__(256) void ssm_phase3(const float* __restrict__ x,
                                                  const float* __restrict__ dtT,
                                                  const float* __restrict__ A_log,
                                                  const float* __restrict__ Bm_,
                                                  const float* __restrict__ Cm_,
                                                  const float* __restrict__ Dv_,
                                                  const float* __restrict__ carryBuf,
                                                  float* __restrict__ out) {
  const int tid = threadIdx.x;
  const int g   = tid >> 4;
  const int n16 = tid & 15;
  const int bid = blockIdx.x;
  const int ht  = bid & 63;
  const int b   = (bid >> 6) & 3;
  const int c   = bid >> 8;
  const int h   = (ht << 4) + g;
  const int lane = tid & 63;
  const int tl   = lane & 15;
  const int idxb = (lane & 48) << 2;

  const float Aneg = -__expf(A_log[h * NN + n16]);
  const float Ae   = Aneg * EXPSCALE;
  const float Cb   = Cm_[h * NN + n16] * Bm_[h * NN + n16];  // C*B folded
  const float Dv   = Dv_[h];

  const f32x4* dp4 = (const f32x4*)(dtT + ((size_t)b * HH + h) * TT + c * TC);
  const float* up  = x + (size_t)b * TT * HH + (size_t)(c * TC + tl) * HH + h;
  float* yp = out + (size_t)b * TT * HH + (size_t)(c * TC + n16) * HH + h;

  float s = carryBuf[(((size_t)c * BB + b) * HH + h) * NN + n16];
  f32x4 d0[4], d1[4];
  float u0, u1;
#pragma unroll
  for (int i = 0; i < 4; ++i) d0[i] = dp4[i];
  u0 = up[0];

#pragma unroll 1
  for (int j = 0; j < TC / 16; j += 2) {
#pragma unroll
    for (int i = 0; i < 4; ++i) d1[i] = dp4[(j + 1) * 4 + i];
    u1 = up[(size_t)(j + 1) * 16 * HH];
    step16_p3(s, d0, u0, idxb, Ae, Cb, Dv, n16, yp);
    yp += 16 * HH;
    if (j + 2 < TC / 16) {
#pragma unroll
      for (int i = 0; i < 4; ++i) d0[i] = dp4[(j + 2) * 4 + i];
      u0 = up[(size_t)(j + 2) * 16 * HH];
    }
    step16_p3(s, d1, u1, idxb, Ae, Cb, Dv, n16, yp);
    yp += 16 * HH;
  }
}

extern "C" void kernel_launch(void* const* d_in, const int* in_sizes, int n_in,
                              void* d_out, int out_size, void* d_ws, size_t ws_size,
                              hipStream_t stream) {
  const float* x     = (const float*)d_in[0];
  const float* A_log = (const float*)d_in[1];
  const float* B_mat = (const float*)d_in[2];
  const float* C_mat = (const float*)d_in[3];
  const float* D_vec = (const float*)d_in[4];
  const float* W_dt  = (const float*)d_in[5];
  const float* b_dt  = (const float*)d_in[6];
  float* out = (float*)d_out;

  char* ws = (char*)d_ws;
  unsigned short* xb  = (unsigned short*)(ws);                 // 16 MB (dead after gemm)
  unsigned short* wb  = (unsigned short*)(ws + 16777216);      //  2 MB (dead after gemm)
  float*          dtT = (float*)(ws + 18874368);               // 32 MB, [B,H,T]
  // sloc/decay reuse the xb region: gemm completes before phase1 in stream order.
  float*          sloc  = (float*)(ws);                        // 4 MB
  float*          decay = (float*)(ws + 4194304);              // 4 MB
  float* stateOut = out + (size_t)BB * TT * HH;

  cvt_f32_bf16<<<(MM * KK / 4 + 255) / 256, 256, 0, stream>>>(x, xb, MM * KK / 4);
  cvt_f32_bf16<<<(GG * KK / 4 + 255) / 256, 256, 0, stream>>>(W_dt, wb, GG * KK / 4);
  gemm_dt<<<dim3(MM / 128, GG / 128), 256, 0, stream>>>(xb, wb, b_dt, dtT);

  const int nblk = BB * (HH / 16) * NCHUNK;   // 4096
  ssm_phase1<<<nblk, 256, 0, stream>>>(x, dtT, A_log, sloc, decay);
  ssm_phase2<<<(BB * HH * NN) / 256, 256, 0, stream>>>(sloc, decay, B_mat, stateOut);
  ssm_phase3<<<nblk, 256, 0, stream>>>(x, dtT, A_log, B_mat, C_mat, D_vec, sloc, out);
}

// Round 7
// 209.596 us; speedup vs baseline: 1.1701x; 1.1061x over previous
//
#include <hip/hip_runtime.h>
#include <stdint.h>

#define BB 4
#define TT 2048
#define HH 1024
#define NN 16
#define KK 1024           // GEMM K  (= H)
#define GG 1024           // GEMM out cols (= H)
#define MM (BB*TT)        // GEMM rows
#define NCHUNK 16
#define TC (TT/NCHUNK)    // 128 timesteps per chunk

#if __has_builtin(__builtin_amdgcn_exp2f)
#define FAST_EXP2(x) __builtin_amdgcn_exp2f(x)
#else
#define FAST_EXP2(x) __expf((x) * 0.6931471805599453f)
#endif
#define EXPSCALE 1.4426950408889634f

typedef __attribute__((ext_vector_type(8))) short short8;
typedef __attribute__((ext_vector_type(4))) float f32x4;

__device__ __forceinline__ unsigned short f2bf(float f) {
  union { float f; unsigned u; } a; a.f = f;
  unsigned u = a.u;
  u += 0x7fffu + ((u >> 16) & 1u);   // round-to-nearest-even
  return (unsigned short)(u >> 16);
}

__global__ __launch_bounds__(256) void cvt_f32_bf16(const float* __restrict__ src,
                                                    unsigned short* __restrict__ dst, int n4) {
  int i = blockIdx.x * blockDim.x + threadIdx.x;
  if (i >= n4) return;
  float4 a = ((const float4*)src)[i];
  ushort4 o;
  o.x = f2bf(a.x); o.y = f2bf(a.y); o.z = f2bf(a.z); o.w = f2bf(a.w);
  ((ushort4*)dst)[i] = o;
}

// dtT[b,h,t] = softplus( sum_k x[(b,t),k]*W[h,k] + b_dt[h] )  -- transposed output
// 128x64 (MxG) tile, 4 blocks/CU for latency hiding at this short-K shape.
__global__ __launch_bounds__(256) void gemm_dt(const unsigned short* __restrict__ xb,
                                               const unsigned short* __restrict__ wb,
                                               const float* __restrict__ b_dt,
                                               float* __restrict__ dtT) {
  __shared__ short lsA[128 * 32];   // 8 KB
  __shared__ short lsB[64 * 32];    // 4 KB
  const int tid  = threadIdx.x;
  const int w    = tid >> 6;
  const int lane = tid & 63;
  const int m0 = blockIdx.x * 128;
  const int g0 = blockIdx.y * 64;

  // staging: A = 4096 elems (2 instr/wave), B = 2048 elems (1 instr/wave)
  const int ea  = w * 1024 + lane * 8;
  const int am0 = ea >> 5,         ak0 = ea & 31;
  const int am1 = (ea + 512) >> 5, ak1 = (ea + 512) & 31;
  const int eb  = w * 512 + lane * 8;
  const int bg0 = eb >> 5,         bk0 = eb & 31;
  const unsigned short* gA0 = xb + (size_t)(m0 + am0) * KK + ak0;
  const unsigned short* gA1 = xb + (size_t)(m0 + am1) * KK + ak1;
  const unsigned short* gB0 = wb + (size_t)(g0 + bg0) * KK + bk0;
  short* lA0 = lsA + w * 1024;
  short* lB0 = lsB + w * 512;

  const int wm   = (w >> 1) * 64;    // wave tile: 64x32
  const int wg   = (w & 1) * 32;
  const int lrow = lane & 15;
  const int lq   = lane >> 4;

  f32x4 acc[4][2];
  const f32x4 zero = {0.f, 0.f, 0.f, 0.f};
#pragma unroll
  for (int i = 0; i < 4; ++i)
#pragma unroll
    for (int j = 0; j < 2; ++j) acc[i][j] = zero;

  for (int kt = 0; kt < KK / 32; ++kt) {
    const int ko = kt * 32;
    __builtin_amdgcn_global_load_lds((__attribute__((address_space(1))) void*)(gA0 + ko),
                                     (__attribute__((address_space(3))) void*)(lA0), 16, 0, 0);
    __builtin_amdgcn_global_load_lds((__attribute__((address_space(1))) void*)(gA1 + ko),
                                     (__attribute__((address_space(3))) void*)(lA0 + 512), 16, 0, 0);
    __builtin_amdgcn_global_load_lds((__attribute__((address_space(1))) void*)(gB0 + ko),
                                     (__attribute__((address_space(3))) void*)(lB0), 16, 0, 0);
    __syncthreads();

    short8 af[4], bfr[2];
#pragma unroll
    for (int mi = 0; mi < 4; ++mi)
      af[mi] = *(const short8*)&lsA[(wm + mi * 16 + lrow) * 32 + lq * 8];
#pragma unroll
    for (int ni = 0; ni < 2; ++ni)
      bfr[ni] = *(const short8*)&lsB[(wg + ni * 16 + lrow) * 32 + lq * 8];
#pragma unroll
    for (int mi = 0; mi < 4; ++mi)
#pragma unroll
      for (int ni = 0; ni < 2; ++ni)
        acc[mi][ni] = __builtin_amdgcn_mfma_f32_16x16x32_bf16(af[mi], bfr[ni], acc[mi][ni], 0, 0, 0);
    __syncthreads();
  }

  // epilogue: 4 consecutive t per lane-fragment -> float4 store into [B,H,T]
  const int b  = m0 >> 11;                      // T=2048 rows per batch, m0 128-aligned
  const int tb = (m0 & (TT - 1)) + wm + lq * 4;
#pragma unroll
  for (int mi = 0; mi < 4; ++mi)
#pragma unroll
    for (int ni = 0; ni < 2; ++ni) {
      const int gcol = g0 + wg + ni * 16 + lrow;
      const float bias = b_dt[gcol];
      f32x4 sp;
#pragma unroll
      for (int r = 0; r < 4; ++r) {
        float z = acc[mi][ni][r] + bias;
        // softplus(z) = max(z,0) + log(1 + exp(-|z|)) using fast exp/log
        sp[r] = fmaxf(z, 0.f) + __logf(1.f + __expf(-fabsf(z)));
      }
      *(f32x4*)&dtT[((size_t)b * HH + gcol) * TT + tb + mi * 16] = sp;
    }
}

// butterfly reduce-scatter over the 16-lane group: lane n ends with sum_p v_p[n]
__device__ __forceinline__ float reduce16(float (&v)[16], int n16) {
#pragma unroll
  for (int i = 0; i < 8; ++i) {
    float lo = v[i], hi = v[i + 8];
    float snd = (n16 & 8) ? lo : hi;
    float rcv = __shfl_xor(snd, 8);
    v[i] = ((n16 & 8) ? hi : lo) + rcv;
  }
#pragma unroll
  for (int i = 0; i < 4; ++i) {
    float lo = v[i], hi = v[i + 4];
    float snd = (n16 & 4) ? lo : hi;
    float rcv = __shfl_xor(snd, 4);
    v[i] = ((n16 & 4) ? hi : lo) + rcv;
  }
#pragma unroll
  for (int i = 0; i < 2; ++i) {
    float lo = v[i], hi = v[i + 2];
    float snd = (n16 & 2) ? lo : hi;
    float rcv = __shfl_xor(snd, 2);
    v[i] = ((n16 & 2) ? hi : lo) + rcv;
  }
  float lo = v[0], hi = v[1];
  float snd = (n16 & 1) ? lo : hi;
  float rcv = __shfl_xor(snd, 1);
  return ((n16 & 1) ? hi : lo) + rcv;
}

// pull u[t=k] from lane g4*16+k of this wave
__device__ __forceinline__ float bcast16(float ureg, int idxbyte) {
  union { float f; int i; } a, r; a.f = ureg;
  r.i = __builtin_amdgcn_ds_bpermute(idxbyte, a.i);
  return r.f;
}

// sequential recurrence in s' units (Bm folded out): s' = a*s' + dt*u
__device__ __forceinline__ void step16_p1(float& s, float& sd, const f32x4* dd, float ureg,
                                          int idxb, float Ae) {
#pragma unroll
  for (int q = 0; q < 4; ++q) {
#pragma unroll
    for (int k = 0; k < 4; ++k) {
      const int kk = q * 4 + k;
      float dtv = dd[q][k];
      float uv  = bcast16(ureg, idxb + kk * 4);
      float ab  = FAST_EXP2(dtv * Ae);
      s = fmaf(ab, s, dtv * uv);
      sd += dtv;
    }
  }
}

__device__ __forceinline__ void step16_p3(float& s, const f32x4* dd, float ureg, int idxb,
                                          float Ae, float Cb, float Dv,
                                          int n16, float* __restrict__ yp) {
  float v[16];
#pragma unroll
  for (int q = 0; q < 4; ++q) {
#pragma unroll
    for (int k = 0; k < 4; ++k) {
      const int kk = q * 4 + k;
      float dtv = dd[q][k];
      float uv  = bcast16(ureg, idxb + kk * 4);
      float ab  = FAST_EXP2(dtv * Ae);
      s = fmaf(ab, s, dtv * uv);
      v[kk] = Cb * s;
    }
  }
  float y = reduce16(v, n16);
  // lane n16 holds u[t0+n16] natively (tl == n16)
  *yp = fmaf(Dv, ureg, y);
}

// ---- chunk-parallel scan, transposed dt + shuffle-broadcast u ------------
// block: 256 threads = 16 h x 16 n. grid: 64 h-tiles x 4 b x NCHUNK c.
__global__ __launch_bounds__(256) void ssm_phase1(const float* __restrict__ x,
                                                  const float* __restrict__ dtT,
                                                  const float* __restrict__ A_log,
                                                  float* __restrict__ sloc,
                                                  float* __restrict__ decay) {
  const int tid = threadIdx.x;
  const int g   = tid >> 4;
  const int n16 = tid & 15;
  const int bid = blockIdx.x;
  const int ht  = bid & 63;
  const int b   = (bid >> 6) & 3;
  const int c   = bid >> 8;
  const int h   = (ht << 4) + g;
  const int lane = tid & 63;
  const int tl   = lane & 15;
  const int idxb = (lane & 48) << 2;   // (lane>>4)*16*4

  const float Aneg = -__expf(A_log[h * NN + n16]);
  const float Ae   = Aneg * EXPSCALE;

  const f32x4* dp4 = (const f32x4*)(dtT + ((size_t)b * HH + h) * TT + c * TC);
  const float* up  = x + (size_t)b * TT * HH + (size_t)(c * TC + tl) * HH + h;

  float s = 0.f, sd = 0.f;
  f32x4 d0[4], d1[4];
  float u0, u1;
#pragma unroll
  for (int i = 0; i < 4; ++i) d0[i] = dp4[i];
  u0 = up[0];

#pragma unroll 1
  for (int j = 0; j < TC / 16; j += 2) {
#pragma unroll
    for (int i = 0; i < 4; ++i) d1[i] = dp4[(j + 1) * 4 + i];
    u1 = up[(size_t)(j + 1) * 16 * HH];
    step16_p1(s, sd, d0, u0, idxb, Ae);
    if (j + 2 < TC / 16) {
#pragma unroll
      for (int i = 0; i < 4; ++i) d0[i] = dp4[(j + 2) * 4 + i];
      u0 = up[(size_t)(j + 2) * 16 * HH];
    }
    step16_p1(s, sd, d1, u1, idxb, Ae);
  }

  const size_t idx = (((size_t)c * BB + b) * HH + h) * NN + n16;
  sloc[idx]  = s;
  decay[idx] = FAST_EXP2(Ae * sd);
}

// phase 2: sequential combine over chunks (s' units); sloc becomes carry-in.
// stateOut converts back to true state: s = Bm * s'.
__global__ __launch_bounds__(256) void ssm_phase2(float* __restrict__ sloc,
                                                  const float* __restrict__ decay,
                                                  const float* __restrict__ Bm_,
                                                  float* __restrict__ stateOut) {
  const int id = blockIdx.x * 256 + threadIdx.x;   // (b,h,n) flat, 65536
  float carry = 0.f;
#pragma unroll
  for (int c = 0; c < NCHUNK; ++c) {
    const size_t idx = (size_t)c * (BB * HH * NN) + id;
    const float sl = sloc[idx];
    const float dc = decay[idx];
    sloc[idx] = carry;
    carry = fmaf(dc, carry, sl);
  }
  stateOut[id] = Bm_[id & (HH * NN - 1)] * carry;
}

// phase 3: scan each chunk from its carry-in (s' units), emitting y.
__global__ __launch_bounds__(256) void ssm_phase3(const float* __restrict__ x,
                                                  const float* __restrict__ dtT,
                                                  const float* __restrict__ A_log,
                                                  const float* __restrict__ Bm_,
                                                  const float* __restrict__ Cm_,
                                                  const float* __restrict__ Dv_,
                                                  const float* __restrict__ carryBuf,
                                                  float* __restrict__ out) {
  const int tid = threadIdx.x;
  const int g   = tid >> 4;
  const int n16 = tid & 15;
  const int bid = blockIdx.x;
  const int ht  = bid & 63;
  const int b   = (bid >> 6) & 3;
  const int c   = bid >> 8;
  const int h   = (ht << 4) + g;
  const int lane = tid & 63;
  const int tl   = lane & 15;
  const int idxb = (lane & 48) << 2;

  const float Aneg = -__expf(A_log[h * NN + n16]);
  const float Ae   = Aneg * EXPSCALE;
  const float Cb   = Cm_[h * NN + n16] * Bm_[h * NN + n16];  // C*B folded
  const float Dv   = Dv_[h];

  const f32x4* dp4 = (const f32x4*)(dtT + ((size_t)b * HH + h) * TT + c * TC);
  const float* up  = x + (size_t)b * TT * HH + (size_t)(c * TC + tl) * HH + h;
  float* yp = out + (size_t)b * TT * HH + (size_t)(c * TC + n16) * HH + h;

  float s = carryBuf[(((size_t)c * BB + b) * HH + h) * NN + n16];
  f32x4 d0[4], d1[4];
  float u0, u1;
#pragma unroll
  for (int i = 0; i < 4; ++i) d0[i] = dp4[i];
  u0 = up[0];

#pragma unroll 1
  for (int j = 0; j < TC / 16; j += 2) {
#pragma unroll
    for (int i = 0; i < 4; ++i) d1[i] = dp4[(j + 1) * 4 + i];
    u1 = up[(size_t)(j + 1) * 16 * HH];
    step16_p3(s, d0, u0, idxb, Ae, Cb, Dv, n16, yp);
    yp += 16 * HH;
    if (j + 2 < TC / 16) {
#pragma unroll
      for (int i = 0; i < 4; ++i) d0[i] = dp4[(j + 2) * 4 + i];
      u0 = up[(size_t)(j + 2) * 16 * HH];
    }
    step16_p3(s, d1, u1, idxb, Ae, Cb, Dv, n16, yp);
    yp += 16 * HH;
  }
}

extern "C" void kernel_launch(void* const* d_in, const int* in_sizes, int n_in,
                              void* d_out, int out_size, void* d_ws, size_t ws_size,
                              hipStream_t stream) {
  const float* x     = (const float*)d_in[0];
  const float* A_log = (const float*)d_in[1];
  const float* B_mat = (const float*)d_in[2];
  const float* C_mat = (const float*)d_in[3];
  const float* D_vec = (const float*)d_in[4];
  const float* W_dt  = (const float*)d_in[5];
  const float* b_dt  = (const float*)d_in[6];
  float* out = (float*)d_out;

  char* ws = (char*)d_ws;
  unsigned short* xb  = (unsigned short*)(ws);                 // 16 MB (dead after gemm)
  unsigned short* wb  = (unsigned short*)(ws + 16777216);      //  2 MB (dead after gemm)
  float*          dtT = (float*)(ws + 18874368);               // 32 MB, [B,H,T]
  // sloc/decay reuse the xb region: gemm completes before phase1 in stream order.
  float*          sloc  = (float*)(ws);                        // 4 MB
  float*          decay = (float*)(ws + 4194304);              // 4 MB
  float* stateOut = out + (size_t)BB * TT * HH;

  cvt_f32_bf16<<<(MM * KK / 4 + 255) / 256, 256, 0, stream>>>(x, xb, MM * KK / 4);
  cvt_f32_bf16<<<(GG * KK / 4 + 255) / 256, 256, 0, stream>>>(W_dt, wb, GG * KK / 4);
  gemm_dt<<<dim3(MM / 128, GG / 64), 256, 0, stream>>>(xb, wb, b_dt, dtT);

  const int nblk = BB * (HH / 16) * NCHUNK;   // 4096
  ssm_phase1<<<nblk, 256, 0, stream>>>(x, dtT, A_log, sloc, decay);
  ssm_phase2<<<(BB * HH * NN) / 256, 256, 0, stream>>>(sloc, decay, B_mat, stateOut);
  ssm_phase3<<<nblk, 256, 0, stream>>>(x, dtT, A_log, B_mat, C_mat, D_vec, sloc, out);
}